// Round 7
// baseline (64.175 us; speedup 1.0000x reference)
//
#include <hip/hip_runtime.h>
#include <hip/hip_cooperative_groups.h>
#include <math.h>
#include <stdint.h>

namespace cg = cooperative_groups;

// Problem constants (fixed by the reference)
constexpr int NQ    = 33;        // N+1
constexpr int NQP   = 34;        // S/S0T leading dim (stride-34 words = 2-way = free)
constexpr int HP    = 36;        // H leading dim (rows 144B -> b128-aligned)
constexpr int NSQ   = NQ * NQ;   // 1089
constexpr int NL    = 8;         // node labels
constexpr int NEL   = 4;         // edge labels
constexpr int NN    = 32;        // N
constexpr int ITERS = 10;        // sinkhorn iterations
constexpr int BLK   = 1024;

// One block per pair; cooperative grid sync + in-kernel normalization.
__global__ __launch_bounds__(BLK, 1) void ged_kernel(
    const float* __restrict__ nw, const float* __restrict__ ew,
    const int* __restrict__ A, const int* __restrict__ labels,
    const int* __restrict__ pairs, float* __restrict__ ged_ws,
    float* __restrict__ out, int P)
{
    __shared__ __align__(16) float S[NQ][NQP];    // S0, scaled in place to V
    __shared__ __align__(16) float S0T[NQ][NQP];  // S0 transposed
    __shared__ __align__(16) float H[5][NQ][HP];  // H[x][i][k]
    __shared__ unsigned char A1s[NQ][36];
    __shared__ unsigned char A2s[NQ][36];
    __shared__ float ncost[NL][NL];
    __shared__ float encost[NL][NL];              // exp(-0.5*ncost)
    __shared__ float ec[NEL][NEL];
    __shared__ __align__(16) float rr[NQ], cc[NQ], rsum[NQ];
    __shared__ float sNID, sEID, sENID;
    __shared__ int l1s[NN], l2s[NN];
    __shared__ float wredq[16], wredl[16];

    const int t  = threadIdx.x;
    const int p  = blockIdx.x;
    const int g1 = pairs[2*p+0], g2 = pairs[2*p+1];

    // ---- phase A: tables (wave 0 lanes), labels, adjacency ----
    if (t < 28) {                            // node substitution costs
        int i = (t>=27)?6 : (t>=25)?5 : (t>=22)?4 : (t>=18)?3 : (t>=13)?2 : (t>=7)?1 : 0;
        int off = (i==0)?0 : (i==1)?7 : (i==2)?13 : (i==3)?18 : (i==4)?22 : (i==5)?25 : 27;
        int j = t - off + i + 1;
        float v = fmaxf(nw[t], 0.f);
        ncost[i][j] = v; ncost[j][i] = v;
        float e = __expf(-0.5f * v);
        encost[i][j] = e; encost[j][i] = e;
    } else if (t == 28) {
        float v = fmaxf(nw[28], 0.f);
        sNID = v; sENID = __expf(-0.5f * v);
    } else if (t >= 32 && t < 38) {          // edge substitution costs
        int q = t - 32;
        // triu_indices(4,k=1): (0,1)(0,2)(0,3)(1,2)(1,3)(2,3)
        int ei = (q<3)?0 : (q<5)?1 : 2;
        int ej = (q<3)?q+1 : (q<5)?q-1 : 3;
        float v = fmaxf(ew[q], 0.f);
        ec[ei][ej] = v; ec[ej][ei] = v;
    } else if (t == 38) {
        sEID = fmaxf(ew[6], 0.f);
    } else if (t >= 40 && t < 48) {          // diagonals
        int q = t - 40;
        ncost[q][q] = 0.f; encost[q][q] = 1.f;
    } else if (t >= 48 && t < 52) {
        int q = t - 48;
        ec[q][q] = 0.f;
    } else if (t >= 56 && t < 56 + NQ) {
        cc[t - 56] = 1.f;                    // sinkhorn col-scale init
    }
    if (t >= 64  && t < 64 + NN)  l1s[t - 64]  = labels[g1*NN + (t - 64)];
    if (t >= 96  && t < 96 + NN)  l2s[t - 96]  = labels[g2*NN + (t - 96)];
    for (int c0 = t; c0 < NSQ; c0 += BLK) {
        int i = c0 / NQ, j = c0 - i*NQ;
        int a1 = (i < NN && j < NN) ? A[g1*NN*NN + i*NN + j] : 0;
        int a2 = (i < NN && j < NN) ? A[g2*NN*NN + i*NN + j] : 0;
        A1s[i][j] = (unsigned char)a1;
        A2s[i][j] = (unsigned char)a2;
    }
    __syncthreads();

    const float NID = sNID, EID = sEID, ENID = sENID;
    const float e01 = ec[0][1], e02 = ec[0][2], e03 = ec[0][3];
    const float e12 = ec[1][2], e13 = ec[1][3], e23 = ec[2][3];

    // ---- phase B: S0 (and transpose) from encost table ----
    for (int c0 = t; c0 < NSQ; c0 += BLK) {
        int i = c0 / NQ, j = c0 - i*NQ;
        float e = (i < NN && j < NN) ? encost[l1s[i]][l2s[j]]
                                     : ((i == NN && j == NN) ? 1.f : ENID);
        S[i][j]   = e;
        S0T[j][i] = e;
    }
    __syncthreads();

    // ---- phase C: sinkhorn on wave-0 lanes 0..32, scaling form ----
    // r[i] = 1/sum_j S0[i][j]*c[j];  c[j] = 1/sum_i S0[i][j]*r[i]; idx 32 -> 1.
    // 4-way partial sums break the serial FMA chain.
    if (t < NQ) {
        const float* Srow = &S[t][0];
        const float* Trow = &S0T[t][0];
        float rval = 1.f;
        for (int it = 0; it < ITERS; ++it) {
            float a0=0.f, a1=0.f, a2=0.f, a3=0.f;
            #pragma unroll
            for (int j = 0; j < 32; j += 4) {
                a0 += Srow[j+0]*cc[j+0]; a1 += Srow[j+1]*cc[j+1];
                a2 += Srow[j+2]*cc[j+2]; a3 += Srow[j+3]*cc[j+3];
            }
            float s = ((a0+a1)+(a2+a3)) + Srow[32]*cc[32];
            rval = (t == NQ-1) ? 1.f : __builtin_amdgcn_rcpf(s);
            rr[t] = rval;
            float b0=0.f, b1=0.f, b2=0.f, b3=0.f;
            #pragma unroll
            for (int j = 0; j < 32; j += 4) {
                b0 += Trow[j+0]*rr[j+0]; b1 += Trow[j+1]*rr[j+1];
                b2 += Trow[j+2]*rr[j+2]; b3 += Trow[j+3]*rr[j+3];
            }
            float s2 = ((b0+b1)+(b2+b3)) + Trow[32]*rr[32];
            cc[t] = (t == NQ-1) ? 1.f : __builtin_amdgcn_rcpf(s2);
        }
        // rowsum of final V: rsum[i] = rr[i] * sum_j S0[i][j]*cc_final[j]
        float a0=0.f, a1=0.f, a2=0.f, a3=0.f;
        #pragma unroll
        for (int j = 0; j < 32; j += 4) {
            a0 += Srow[j+0]*cc[j+0]; a1 += Srow[j+1]*cc[j+1];
            a2 += Srow[j+2]*cc[j+2]; a3 += Srow[j+3]*cc[j+3];
        }
        float sf = ((a0+a1)+(a2+a3)) + Srow[32]*cc[32];
        rsum[t] = rval * sf;
    }
    __syncthreads();

    // ---- phase D: materialize V = diag(r) S0 diag(c) in place ----
    for (int c0 = t; c0 < NSQ; c0 += BLK) {
        int i = c0 / NQ, j = c0 - i*NQ;
        S[i][j] *= rr[i] * cc[j];
    }
    __syncthreads();

    // ---- phase E: H[x][i][k]; p0 recovered from rsum (no selects for y=0) ----
    for (int c0 = t; c0 < NSQ; c0 += BLK) {
        int i = c0 / NQ, k = c0 - i*NQ;
        const float* Si = &S[i][0];
        const uint32_t* Aw = (const uint32_t*)&A2s[k][0];
        float p1=0.f, p2=0.f, p3=0.f, p4=0.f;
        #pragma unroll
        for (int l = 0; l < NQ; ++l) {
            float v = Si[l];
            int a2v = (int)((Aw[l >> 2] >> ((l & 3) * 8)) & 255u);
            p1 += (a2v == 1) ? v : 0.f;
            p2 += (a2v == 2) ? v : 0.f;
            p3 += (a2v == 3) ? v : 0.f;
            p4 += (a2v == 4) ? v : 0.f;
        }
        float t4 = (p1 + p2) + (p3 + p4);
        float p0 = rsum[i] - t4;
        H[0][i][k] = EID * t4;
        H[1][i][k] = EID * p0 +            e01*p2 + e02*p3 + e03*p4;
        H[2][i][k] = EID * p0 + e01*p1 +            e12*p3 + e13*p4;
        H[3][i][k] = EID * p0 + e02*p1 + e12*p2 +            e23*p4;
        H[4][i][k] = EID * p0 + e03*p1 + e13*p2 + e23*p3;
    }
    __syncthreads();

    // ---- phase F: quad + linear, j-tiled (thread = (j, group of 3 i's)) ----
    float qpart = 0.f, lpart = 0.f;
    if (t < 363) {
        const int j  = t / 11;
        const int ig = t - j*11;
        float Vr[34];
        const float2* Sj2 = (const float2*)&S[j][0];
        #pragma unroll
        for (int m = 0; m < 17; ++m) {
            float2 w = Sj2[m];
            Vr[2*m] = w.x; Vr[2*m+1] = w.y;
        }
        #pragma unroll
        for (int ii = 0; ii < 3; ++ii) {
            const int i = ig*3 + ii;
            const int x = A1s[i][j];
            const float* Hx = &H[x][i][0];
            float d0=0.f, d1=0.f, d2=0.f, d3=0.f;
            #pragma unroll
            for (int k = 0; k < 32; k += 4) {
                d0 += Vr[k+0]*Hx[k+0]; d1 += Vr[k+1]*Hx[k+1];
                d2 += Vr[k+2]*Hx[k+2]; d3 += Vr[k+3]*Hx[k+3];
            }
            qpart += ((d0+d1)+(d2+d3)) + Vr[32]*Hx[32];
            float d;
            if (i < NN && j < NN) d = ncost[l1s[i]][l2s[j]];
            else                  d = (i == NN && j == NN) ? 0.f : NID;
            lpart += d * S[i][j];
        }
    }

    #pragma unroll
    for (int off = 32; off > 0; off >>= 1) {
        qpart += __shfl_down(qpart, off);
        lpart += __shfl_down(lpart, off);
    }
    if ((t & 63) == 0) { wredq[t>>6] = qpart; wredl[t>>6] = lpart; }
    __syncthreads();
    if (t < 16) {
        float q = wredq[t], l = wredl[t];
        q += __shfl_down(q, 8); l += __shfl_down(l, 8);
        q += __shfl_down(q, 4); l += __shfl_down(l, 4);
        q += __shfl_down(q, 2); l += __shfl_down(l, 2);
        q += __shfl_down(q, 1); l += __shfl_down(l, 1);
        if (t == 0) ged_ws[p] = 0.5f * q + l;
    }
    __threadfence();            // make ged_ws[p] visible device-wide before the grid barrier

    // ---- grid-wide barrier, then each block normalizes its own output ----
    cg::this_grid().sync();

    if (t < 64) {
        float mn = 1e30f, mx = -1e30f;
        for (int i = t; i < P; i += 64) {
            float g = ged_ws[i];
            mn = fminf(mn, g); mx = fmaxf(mx, g);
        }
        #pragma unroll
        for (int off = 32; off > 0; off >>= 1) {
            mn = fminf(mn, __shfl_xor(mn, off));
            mx = fmaxf(mx, __shfl_xor(mx, off));
        }
        if (t == 0) out[p] = (ged_ws[p] - mn) / (mx - mn);
    }
}

extern "C" void kernel_launch(void* const* d_in, const int* in_sizes, int n_in,
                              void* d_out, int out_size, void* d_ws, size_t ws_size,
                              hipStream_t stream) {
    const float* nw     = (const float*)d_in[0];
    const float* ew     = (const float*)d_in[1];
    const int*   A      = (const int*)d_in[2];
    const int*   labels = (const int*)d_in[3];
    const int*   pairs  = (const int*)d_in[4];
    int P = in_sizes[4] / 2;

    float* ged_ws = (float*)d_ws;
    float* out    = (float*)d_out;

    void* args[] = { (void*)&nw, (void*)&ew, (void*)&A, (void*)&labels,
                     (void*)&pairs, (void*)&ged_ws, (void*)&out, (void*)&P };
    hipLaunchCooperativeKernel((void*)ged_kernel, dim3(P), dim3(BLK), args, 0, stream);
}

// Round 8
// 20.589 us; speedup vs baseline: 3.1169x; 3.1169x over previous
//
#include <hip/hip_runtime.h>
#include <math.h>
#include <stdint.h>

// Problem constants (fixed by the reference)
constexpr int NQ    = 33;        // N+1
constexpr int NQP   = 34;        // S/S0T leading dim (stride-34 words = 2-way = free)
constexpr int HP    = 36;        // H leading dim (rows 144B -> b128-aligned)
constexpr int NSQ   = NQ * NQ;   // 1089
constexpr int NL    = 8;         // node labels
constexpr int NEL   = 4;         // edge labels
constexpr int NN    = 32;        // N
constexpr int ITERS = 10;        // sinkhorn iterations
constexpr int BLK   = 1024;

// One block per pair. ged[p] -> ged_ws.
__global__ __launch_bounds__(BLK, 1) void ged_kernel(
    const float* __restrict__ nw, const float* __restrict__ ew,
    const int* __restrict__ A, const int* __restrict__ labels,
    const int* __restrict__ pairs, float* __restrict__ ged_ws)
{
    __shared__ __align__(16) float S[NQ][NQP];    // S0, scaled in place to V
    __shared__ __align__(16) float S0T[NQ][NQP];  // S0 transposed
    __shared__ __align__(16) float H[5][NQ][HP];  // H[x][i][k]
    __shared__ unsigned char A1s[NQ][36];
    __shared__ unsigned char A2s[NQ][36];
    __shared__ float ncost[NL][NL];
    __shared__ float encost[NL][NL];              // exp(-0.5*ncost)
    __shared__ float ec[NEL][NEL];
    __shared__ __align__(16) float rr[NQ], cc[NQ], rsum[NQ];
    __shared__ float sNID, sEID, sENID;
    __shared__ int l1s[NN], l2s[NN];
    __shared__ float wredq[16], wredl[16];

    const int t  = threadIdx.x;
    const int p  = blockIdx.x;
    const int g1 = pairs[2*p+0], g2 = pairs[2*p+1];

    // ---- phase A: tables (wave 0 lanes), labels, adjacency ----
    if (t < 28) {                            // node substitution costs
        int i = (t>=27)?6 : (t>=25)?5 : (t>=22)?4 : (t>=18)?3 : (t>=13)?2 : (t>=7)?1 : 0;
        int off = (i==0)?0 : (i==1)?7 : (i==2)?13 : (i==3)?18 : (i==4)?22 : (i==5)?25 : 27;
        int j = t - off + i + 1;
        float v = fmaxf(nw[t], 0.f);
        ncost[i][j] = v; ncost[j][i] = v;
        float e = __expf(-0.5f * v);
        encost[i][j] = e; encost[j][i] = e;
    } else if (t == 28) {
        float v = fmaxf(nw[28], 0.f);
        sNID = v; sENID = __expf(-0.5f * v);
    } else if (t >= 32 && t < 38) {          // edge substitution costs
        int q = t - 32;
        // triu_indices(4,k=1): (0,1)(0,2)(0,3)(1,2)(1,3)(2,3)
        int ei = (q<3)?0 : (q<5)?1 : 2;
        int ej = (q<3)?q+1 : (q<5)?q-1 : 3;
        float v = fmaxf(ew[q], 0.f);
        ec[ei][ej] = v; ec[ej][ei] = v;
    } else if (t == 38) {
        sEID = fmaxf(ew[6], 0.f);
    } else if (t >= 40 && t < 48) {          // diagonals
        int q = t - 40;
        ncost[q][q] = 0.f; encost[q][q] = 1.f;
    } else if (t >= 48 && t < 52) {
        int q = t - 48;
        ec[q][q] = 0.f;
    }
    if (t >= 64  && t < 64 + NN)  l1s[t - 64]  = labels[g1*NN + (t - 64)];
    if (t >= 96  && t < 96 + NN)  l2s[t - 96]  = labels[g2*NN + (t - 96)];
    for (int c0 = t; c0 < NSQ; c0 += BLK) {
        int i = c0 / NQ, j = c0 - i*NQ;
        int a1 = (i < NN && j < NN) ? A[g1*NN*NN + i*NN + j] : 0;
        int a2 = (i < NN && j < NN) ? A[g2*NN*NN + i*NN + j] : 0;
        A1s[i][j] = (unsigned char)a1;
        A2s[i][j] = (unsigned char)a2;
    }
    __syncthreads();

    const float NID = sNID, EID = sEID, ENID = sENID;
    const float e01 = ec[0][1], e02 = ec[0][2], e03 = ec[0][3];
    const float e12 = ec[1][2], e13 = ec[1][3], e23 = ec[2][3];

    // ---- phase B: S0 (and transpose) from encost table ----
    for (int c0 = t; c0 < NSQ; c0 += BLK) {
        int i = c0 / NQ, j = c0 - i*NQ;
        float e = (i < NN && j < NN) ? encost[l1s[i]][l2s[j]]
                                     : ((i == NN && j == NN) ? 1.f : ENID);
        S[i][j]   = e;
        S0T[j][i] = e;
    }
    __syncthreads();

    // ---- phase C: in-register sinkhorn on wave 0, 2 lanes per row ----
    // Lane L<32: row id=L, elements 0..16.  Lane L>=32: id=L-32, elements 17..32.
    // cval/rval copies live in both halves; lane 63's copy is forced to 1.0 and
    // stands in for c[32]=r[32]=1 (lane 31 keeps the true c31/r31 copy).
    // Setup is read from LDS (cheap) -- the round-5 mistake was global+expf setup.
    if (t < 64) {
        const int half = t >> 5;
        const int id   = t & 31;
        float sreg[17], treg[17];
        int   idxr[17];
        #pragma unroll
        for (int m = 0; m < 17; ++m) {
            int hs = 17 + m;
            int src = half ? ((hs <= 31) ? hs : 63) : m;
            idxr[m] = src << 2;
        }
        #pragma unroll
        for (int m = 0; m < 17; ++m) {
            int j = half ? (17 + m) : m;               // half1 m<=15 -> j<=32
            float sv = (half && m == 16) ? 0.f : S[id][j];
            float tv = (half && m == 16) ? 0.f : S0T[id][j];
            sreg[m] = sv; treg[m] = tv;
        }

        float cval = 1.0f, rval = 1.0f;
        for (int it = 0; it < ITERS; ++it) {
            float a0=0.f, a1=0.f, a2=0.f, a3=0.f;
            #pragma unroll
            for (int m = 0; m < 17; ++m) {
                float cm = __int_as_float(
                    __builtin_amdgcn_ds_bpermute(idxr[m], __float_as_int(cval)));
                if ((m & 3) == 0) a0 += sreg[m]*cm;
                else if ((m & 3) == 1) a1 += sreg[m]*cm;
                else if ((m & 3) == 2) a2 += sreg[m]*cm;
                else a3 += sreg[m]*cm;
            }
            float part = (a0+a1)+(a2+a3);
            part += __shfl_xor(part, 32);
            rval = __builtin_amdgcn_rcpf(part);
            if (t == 63) rval = 1.0f;                  // r[32] = 1
            float b0=0.f, b1=0.f, b2=0.f, b3=0.f;
            #pragma unroll
            for (int m = 0; m < 17; ++m) {
                float rm = __int_as_float(
                    __builtin_amdgcn_ds_bpermute(idxr[m], __float_as_int(rval)));
                if ((m & 3) == 0) b0 += treg[m]*rm;
                else if ((m & 3) == 1) b1 += treg[m]*rm;
                else if ((m & 3) == 2) b2 += treg[m]*rm;
                else b3 += treg[m]*rm;
            }
            float part2 = (b0+b1)+(b2+b3);
            part2 += __shfl_xor(part2, 32);
            cval = __builtin_amdgcn_rcpf(part2);
            if (t == 63) cval = 1.0f;                  // c[32] = 1
        }

        // rsum[i] = r_final[i] * sum_j S0[i][j] * c_final[j]  (rows 0..31)
        float a0=0.f, a1=0.f, a2=0.f, a3=0.f;
        #pragma unroll
        for (int m = 0; m < 17; ++m) {
            float cm = __int_as_float(
                __builtin_amdgcn_ds_bpermute(idxr[m], __float_as_int(cval)));
            if ((m & 3) == 0) a0 += sreg[m]*cm;
            else if ((m & 3) == 1) a1 += sreg[m]*cm;
            else if ((m & 3) == 2) a2 += sreg[m]*cm;
            else a3 += sreg[m]*cm;
        }
        float part = (a0+a1)+(a2+a3);
        part += __shfl_xor(part, 32);
        if (!half) { rr[id] = rval; cc[id] = cval; rsum[id] = rval * part; }

        // row 32: rr=cc=1; rsum[32] = ENID * sum_{j<32} c[j] + 1
        float csum = cval;                              // lanes 0..31 hold true c[id]
        csum += __shfl_xor(csum, 16);
        csum += __shfl_xor(csum, 8);
        csum += __shfl_xor(csum, 4);
        csum += __shfl_xor(csum, 2);
        csum += __shfl_xor(csum, 1);
        if (t == 0) {
            rr[32] = 1.f; cc[32] = 1.f;
            rsum[32] = ENID * csum + 1.0f;
        }
    }
    __syncthreads();

    // ---- phase D: materialize V = diag(r) S0 diag(c) in place ----
    for (int c0 = t; c0 < NSQ; c0 += BLK) {
        int i = c0 / NQ, j = c0 - i*NQ;
        S[i][j] *= rr[i] * cc[j];
    }
    __syncthreads();

    // ---- phase E: H[x][i][k]; p0 recovered from rsum (no selects for y=0) ----
    for (int c0 = t; c0 < NSQ; c0 += BLK) {
        int i = c0 / NQ, k = c0 - i*NQ;
        const float* Si = &S[i][0];
        const uint32_t* Aw = (const uint32_t*)&A2s[k][0];
        float p1=0.f, p2=0.f, p3=0.f, p4=0.f;
        #pragma unroll
        for (int l = 0; l < NQ; ++l) {
            float v = Si[l];
            int a2v = (int)((Aw[l >> 2] >> ((l & 3) * 8)) & 255u);
            p1 += (a2v == 1) ? v : 0.f;
            p2 += (a2v == 2) ? v : 0.f;
            p3 += (a2v == 3) ? v : 0.f;
            p4 += (a2v == 4) ? v : 0.f;
        }
        float t4 = (p1 + p2) + (p3 + p4);
        float p0 = rsum[i] - t4;
        H[0][i][k] = EID * t4;
        H[1][i][k] = EID * p0 +            e01*p2 + e02*p3 + e03*p4;
        H[2][i][k] = EID * p0 + e01*p1 +            e12*p3 + e13*p4;
        H[3][i][k] = EID * p0 + e02*p1 + e12*p2 +            e23*p4;
        H[4][i][k] = EID * p0 + e03*p1 + e13*p2 + e23*p3;
    }
    __syncthreads();

    // ---- phase F: quad + linear, j-tiled (thread = (j, group of 3 i's)) ----
    float qpart = 0.f, lpart = 0.f;
    if (t < 363) {
        const int j  = t / 11;
        const int ig = t - j*11;
        float Vr[34];
        const float2* Sj2 = (const float2*)&S[j][0];
        #pragma unroll
        for (int m = 0; m < 17; ++m) {
            float2 w = Sj2[m];
            Vr[2*m] = w.x; Vr[2*m+1] = w.y;
        }
        #pragma unroll
        for (int ii = 0; ii < 3; ++ii) {
            const int i = ig*3 + ii;
            const int x = A1s[i][j];
            const float* Hx = &H[x][i][0];
            float d0=0.f, d1=0.f, d2=0.f, d3=0.f;
            #pragma unroll
            for (int k = 0; k < 32; k += 4) {
                d0 += Vr[k+0]*Hx[k+0]; d1 += Vr[k+1]*Hx[k+1];
                d2 += Vr[k+2]*Hx[k+2]; d3 += Vr[k+3]*Hx[k+3];
            }
            qpart += ((d0+d1)+(d2+d3)) + Vr[32]*Hx[32];
            float d;
            if (i < NN && j < NN) d = ncost[l1s[i]][l2s[j]];
            else                  d = (i == NN && j == NN) ? 0.f : NID;
            lpart += d * S[i][j];
        }
    }

    #pragma unroll
    for (int off = 32; off > 0; off >>= 1) {
        qpart += __shfl_down(qpart, off);
        lpart += __shfl_down(lpart, off);
    }
    if ((t & 63) == 0) { wredq[t>>6] = qpart; wredl[t>>6] = lpart; }
    __syncthreads();
    if (t < 16) {
        float q = wredq[t], l = wredl[t];
        q += __shfl_down(q, 8); l += __shfl_down(l, 8);
        q += __shfl_down(q, 4); l += __shfl_down(l, 4);
        q += __shfl_down(q, 2); l += __shfl_down(l, 2);
        q += __shfl_down(q, 1); l += __shfl_down(l, 1);
        if (t == 0) ged_ws[p] = 0.5f * q + l;
    }
}

// out = (ged - min)/(max - min)
__global__ __launch_bounds__(64) void norm_kernel(
    const float* __restrict__ ged, float* __restrict__ out, int P)
{
    int t = threadIdx.x;
    float mn = 1e30f, mx = -1e30f;
    for (int i = t; i < P; i += 64) {
        float g = ged[i];
        mn = fminf(mn, g); mx = fmaxf(mx, g);
    }
    #pragma unroll
    for (int off = 32; off > 0; off >>= 1) {
        mn = fminf(mn, __shfl_xor(mn, off));
        mx = fmaxf(mx, __shfl_xor(mx, off));
    }
    float inv = 1.f / (mx - mn);
    for (int i = t; i < P; i += 64) out[i] = (ged[i] - mn) * inv;
}

extern "C" void kernel_launch(void* const* d_in, const int* in_sizes, int n_in,
                              void* d_out, int out_size, void* d_ws, size_t ws_size,
                              hipStream_t stream) {
    const float* nw     = (const float*)d_in[0];
    const float* ew     = (const float*)d_in[1];
    const int*   A      = (const int*)d_in[2];
    const int*   labels = (const int*)d_in[3];
    const int*   pairs  = (const int*)d_in[4];
    const int P = in_sizes[4] / 2;

    float* ged_ws = (float*)d_ws;

    ged_kernel<<<P, BLK, 0, stream>>>(nw, ew, A, labels, pairs, ged_ws);
    norm_kernel<<<1, 64, 0, stream>>>(ged_ws, (float*)d_out, P);
}